// Round 3
// baseline (444.240 us; speedup 1.0000x reference)
//
#include <hip/hip_runtime.h>
#include <stdint.h>

typedef unsigned short u16;
typedef unsigned int   u32;

#define N_NODES  100000
#define N_EDGES  1600000
#define DFEAT    128
#define N_GRAPHS 512

#define NBKT   391    // buckets of 256 nodes (ceil(N/256))
#define EPB    8192   // edges per block in hist/scatter
#define NBLK_E 196    // ceil(N_EDGES/EPB)
#define LBUF   8192   // per-bucket capacity (mean 4096, sigma ~64)

typedef float f32x4 __attribute__((ext_vector_type(4)));
typedef short s16x8 __attribute__((ext_vector_type(8)));

__device__ __forceinline__ float bflo(u32 u) { return __uint_as_float(u << 16); }
__device__ __forceinline__ float bfhi(u32 u) { return __uint_as_float(u & 0xffff0000u); }
__device__ __forceinline__ u16 f2bf(float f) {
  u32 u = __float_as_uint(f);
  return (u16)((u + 0x7fffu + ((u >> 16) & 1u)) >> 16);   // RNE
}
__device__ __forceinline__ u32 pack2(float f0, float f1) {
  return (u32)f2bf(f0) | ((u32)f2bf(f1) << 16);
}

__device__ __forceinline__ int ld_src(const int* ei, int m, int e) {
  return m ? ei[2 * e] : ei[e];
}
__device__ __forceinline__ int ld_dst(const int* ei, int m, int e) {
  return m ? ei[2 * (N_EDGES + e)] : ei[N_EDGES + e];
}

// block-local int64-vs-int32 detect (odd words of first 64 edge slots all zero <=> int64)
__device__ __forceinline__ int detect_m_block(const int* __restrict__ ei, int* sm) {
  int t = threadIdx.x;
  if (t < 64) {
    int v = ei[2 * t + 1];
    unsigned long long b = __ballot(v != 0);
    if (t == 0) *sm = (b == 0ull) ? 1 : 0;
  }
  __syncthreads();
  return *sm;
}

// ---------------- pass A: per-block bucket histogram + W cvt + flag ----------------
__global__ __launch_bounds__(256) void histA_k(const int* __restrict__ ei,
                                               int* __restrict__ ghist,
                                               const float* __restrict__ W1,
                                               const float* __restrict__ W2,
                                               const float* __restrict__ W3,
                                               u16* __restrict__ T1, u16* __restrict__ T2,
                                               u16* __restrict__ T3, int* __restrict__ flag) {
  int t = threadIdx.x, b = blockIdx.x;
  if (b >= NBLK_E) {
    int r = b - NBLK_E;
    if (r < 3) {   // W transpose+convert
      const float* W = (r == 0) ? W1 : (r == 1) ? W2 : W3;
      u16* T         = (r == 0) ? T1 : (r == 1) ? T2 : T3;
      for (int i = t; i < DFEAT * DFEAT; i += 256) {
        int n = i >> 7, k = i & 127;
        T[i] = f2bf(W[k * DFEAT + n]);
      }
    } else {       // flag for pool_k
      if (t < 64) {
        int v = ei[2 * t + 1];
        unsigned long long mm = __ballot(v != 0);
        if (t == 0) *flag = (mm == 0ull) ? 1 : 0;
      }
    }
    return;
  }
  __shared__ int sm;
  __shared__ int hist[NBKT];
  int m = detect_m_block(ei, &sm);
  for (int i = t; i < NBKT; i += 256) hist[i] = 0;
  __syncthreads();
  int e0 = b * EPB;
#pragma unroll
  for (int p = 0; p < EPB / 256; p++) {
    int e = e0 + p * 256 + t;
    if (e < N_EDGES) atomicAdd(&hist[ld_dst(ei, m, e) >> 8], 1);
  }
  __syncthreads();
  for (int i = t; i < NBKT; i += 256) ghist[b * NBKT + i] = hist[i];
}

// ---------------- pass B: per-bucket exclusive scan over blocks ----------------
__global__ __launch_bounds__(256) void scanB1_k(int* __restrict__ ghist,
                                                int* __restrict__ gtot) {
  __shared__ int ts[256];
  int t = threadIdx.x, k = blockIdx.x;
  int v = (t < NBLK_E) ? ghist[t * NBKT + k] : 0;
  ts[t] = v;
  for (int off = 1; off < 256; off <<= 1) {
    __syncthreads(); int add = (t >= off) ? ts[t - off] : 0;
    __syncthreads(); ts[t] += add;
  }
  __syncthreads();
  if (t < NBLK_E) ghist[t * NBKT + k] = ts[t] - v;
  if (t == 255) gtot[k] = ts[255];
}

// in-block exclusive scan of gtot[NBKT] -> bb[NBKT+1]
__device__ __forceinline__ void scan_gtot_block(const int* __restrict__ gtot,
                                                int* bb, int* sc) {
  int t = threadIdx.x;
  int v0 = gtot[t];
  sc[t] = v0;
  for (int off = 1; off < 256; off <<= 1) {
    __syncthreads(); int add = (t >= off) ? sc[t - off] : 0;
    __syncthreads(); sc[t] += add;
  }
  __syncthreads();
  bb[t] = sc[t] - v0;
  int base256 = sc[255];
  __syncthreads();
  int v1 = (t < NBKT - 256) ? gtot[256 + t] : 0;
  sc[t] = v1;
  for (int off = 1; off < 256; off <<= 1) {
    __syncthreads(); int add = (t >= off) ? sc[t - off] : 0;
    __syncthreads(); sc[t] += add;
  }
  __syncthreads();
  if (t < NBKT - 256) bb[256 + t] = base256 + sc[t] - v1;
  if (t == 0) bb[NBKT] = N_EDGES;
  __syncthreads();
}

// ---------------- pass C: place edges into bucket regions ----------------
__global__ __launch_bounds__(256) void scatterC_k(const int* __restrict__ ei,
                                                  const int* __restrict__ obase,
                                                  const int* __restrict__ gtot,
                                                  u32* __restrict__ colpk) {
  __shared__ int sm;
  __shared__ int cur[NBKT];
  __shared__ int bb[NBKT + 1];
  __shared__ int sc[256];
  int t = threadIdx.x, b = blockIdx.x;
  int m = detect_m_block(ei, &sm);
  scan_gtot_block(gtot, bb, sc);
  for (int i = t; i < NBKT; i += 256) cur[i] = bb[i] + obase[b * NBKT + i];
  __syncthreads();
  int e0 = b * EPB;
#pragma unroll
  for (int p = 0; p < EPB / 256; p++) {
    int e = e0 + p * 256 + t;
    if (e < N_EDGES) {
      int d = ld_dst(ei, m, e);
      int s = ld_src(ei, m, e);
      int pos = atomicAdd(&cur[d >> 8], 1);
      colpk[pos] = (u32)s | ((u32)(d & 255) << 24);
    }
  }
}

// ---------------- pass D: degrees, rowptr, dinv, exact CSR placement ----------------
__global__ __launch_bounds__(256) void fillD_k(const int* __restrict__ gtot,
                                               const u32* __restrict__ colpk,
                                               int* __restrict__ colarr,
                                               int* __restrict__ rowptr,
                                               float* __restrict__ dinv) {
  __shared__ int hist[256];
  __shared__ int cur[256];
  __shared__ int lbuf[LBUF];
  __shared__ int bb[NBKT + 1];
  __shared__ int sc[256];
  int t = threadIdx.x, b = blockIdx.x;
  scan_gtot_block(gtot, bb, sc);
  int base = bb[b], end = bb[b + 1], cnt = end - base;
  hist[t] = 0;
  __syncthreads();
  for (int i = t; i < cnt; i += 256) atomicAdd(&hist[colpk[base + i] >> 24], 1);
  __syncthreads();
  int c = hist[t];
  cur[t] = c;
  for (int off = 1; off < 256; off <<= 1) {
    __syncthreads(); int add = (t >= off) ? cur[t - off] : 0;
    __syncthreads(); cur[t] += add;
  }
  __syncthreads();
  int excl = cur[t] - c;
  int node = b * 256 + t;
  if (node < N_NODES) {
    rowptr[node] = base + excl;
    dinv[node] = rsqrtf((float)(c + 1));      // +1 self-loop
  }
  if (b == NBKT - 1 && t == 0) rowptr[N_NODES] = N_EDGES;
  __syncthreads();
  cur[t] = excl;
  __syncthreads();
  for (int i = t; i < cnt; i += 256) {
    u32 v = colpk[base + i];
    int slot = atomicAdd(&cur[v >> 24], 1);
    if (slot < LBUF) lbuf[slot] = (int)(v & 0x00FFFFFFu);
  }
  __syncthreads();
  for (int i = t; i < cnt; i += 256) colarr[base + i] = lbuf[i];
}

// ---------------- MFMA GEMM: Y[r,:] = bf16((X @ W)[r,:] * dinv[r]) ----------------
// 64-row tile, 256 threads / 4 waves, one 16-row strip per wave.
// W read directly from global (32KB, L1/L2-resident across all blocks) -> only
// sX in LDS (17.4KB) -> ~6 blocks/CU co-resident (vs 1-2 before): staging
// latency of one block hides under compute/epilogue of others.
#define LP 136       // LDS pitch in ushorts (272B, 16B-aligned rows)
#define GROWS 64     // rows per block

__global__ __launch_bounds__(256, 6) void gemm_scale_k(const void* __restrict__ Xv,
                                                       int x_is_f32,
                                                       const u16* __restrict__ Wt,
                                                       const float* __restrict__ dinv,
                                                       u16* __restrict__ Y, int nrows) {
  __shared__ u16 sX[GROWS * LP];
  int tid = threadIdx.x;
  int r0 = blockIdx.x * GROWS;

  if (x_is_f32) {
    const float* Xf = (const float*)Xv;
    for (int c = tid; c < GROWS * 16; c += 256) {
      int row = c >> 4, off = (c & 15) * 8;
      int grow = r0 + row;
      uint4 o = make_uint4(0, 0, 0, 0);
      if (grow < nrows) {
        const float* px = Xf + (size_t)grow * DFEAT + off;
        float4 v0 = *(const float4*)px;
        float4 v1 = *(const float4*)(px + 4);
        o.x = pack2(v0.x, v0.y); o.y = pack2(v0.z, v0.w);
        o.z = pack2(v1.x, v1.y); o.w = pack2(v1.z, v1.w);
      }
      *(uint4*)(&sX[row * LP + off]) = o;
    }
  } else {
    const u16* Xb = (const u16*)Xv;
    for (int c = tid; c < GROWS * 16; c += 256) {
      int row = c >> 4, off = (c & 15) * 8;
      int grow = r0 + row;
      uint4 v = make_uint4(0, 0, 0, 0);
      if (grow < nrows) v = *(const uint4*)(Xb + (size_t)grow * DFEAT + off);
      *(uint4*)(&sX[row * LP + off]) = v;
    }
  }
  __syncthreads();

  int wave = tid >> 6, lane = tid & 63;
  int q = lane >> 4, r = lane & 15;
  int wr0 = wave * 16;

  f32x4 acc[8];
#pragma unroll
  for (int i = 0; i < 8; i++) acc[i] = (f32x4){0.f, 0.f, 0.f, 0.f};

  // per-lane W base: row r, column q*8 (B-fragment rows stride 16)
  const u16* Wb = Wt + (size_t)r * DFEAT + q * 8;

#pragma unroll
  for (int kk = 0; kk < 4; kk++) {
    int k0 = kk * 32;
    s16x8 a0 = *(const s16x8*)(&sX[(wr0 + r) * LP + k0 + q * 8]);
#pragma unroll
    for (int nt = 0; nt < 8; nt++) {
      s16x8 b = *(const s16x8*)(Wb + nt * 16 * DFEAT + k0);
      acc[nt] = __builtin_amdgcn_mfma_f32_16x16x32_bf16(a0, b, acc[nt], 0, 0, 0);
    }
  }

#pragma unroll
  for (int i = 0; i < 4; i++) {
    int grow = r0 + wr0 + q * 4 + i;
    if (grow < nrows) {
      float dv = dinv[grow];
#pragma unroll
      for (int nt = 0; nt < 8; nt++) {
        Y[(size_t)grow * DFEAT + nt * 16 + r] = f2bf(acc[nt][i] * dv);
      }
    }
  }
}

// ---------------- aggregation (bf16 rows, f32 accumulate) ----------------
// XCD feature-split: blocks on XCDs 0-3 (blockIdx%8 in 0..3) gather only bytes
// [0,128) of each HS row; XCDs 4-7 gather bytes [128,256). Per-XCD gather
// working set 12.8MB. unroll-4 (VGPR ~28) — unroll-8 cost occupancy with no
// BW gain (r1); BW plateaus ~3.5 TB/s across 45-68% occupancy -> path limit.
struct Acc8 {
  float a0, a1, a2, a3, a4, a5, a6, a7;
  __device__ __forceinline__ void add(uint4 v) {
    a0 += bflo(v.x); a1 += bfhi(v.x); a2 += bflo(v.y); a3 += bfhi(v.y);
    a4 += bflo(v.z); a5 += bfhi(v.z); a6 += bflo(v.w); a7 += bfhi(v.w);
  }
};

#define AGG_NB_HALF 3125               // node-blocks of 32 per half
#define AGG_GRID    6256               // 782 * 8 (covers both halves, few guarded)

__global__ __launch_bounds__(256) void agg_k(const u32* __restrict__ HS,
                                             const float* __restrict__ dinv,
                                             const int* __restrict__ rowptr,
                                             const int* __restrict__ colidx,
                                             const float* __restrict__ bias,
                                             u32* __restrict__ OUT, int do_relu) {
  int t = threadIdx.x;
  int bid = blockIdx.x;
  int res = bid & 7;                   // XCD residue (round-robin dispatch)
  int half = res >> 2;                 // 0: features 0-63, 1: features 64-127
  int nb = (bid >> 3) * 4 + (res & 3); // node-block index within this half
  if (nb >= AGG_NB_HALF) return;

  int node = nb * 32 + (t >> 3);
  int fp = t & 7;                      // which 16B chunk within the 128B half
  int cbase = half * 32 + fp * 4;      // u32 offset within the 64-u32 row

  int s = rowptr[node], e = rowptr[node + 1];

  Acc8 A;
  uint4 v = *(const uint4*)(HS + (size_t)node * 64 + cbase);   // self row
  A.a0 = bflo(v.x); A.a1 = bfhi(v.x); A.a2 = bflo(v.y); A.a3 = bfhi(v.y);
  A.a4 = bflo(v.z); A.a5 = bfhi(v.z); A.a6 = bflo(v.w); A.a7 = bfhi(v.w);

  int j = s;
  for (; j + 4 <= e; j += 4) {
    int i0 = colidx[j], i1 = colidx[j + 1], i2 = colidx[j + 2], i3 = colidx[j + 3];
    uint4 w0 = *(const uint4*)(HS + (size_t)i0 * 64 + cbase);
    uint4 w1 = *(const uint4*)(HS + (size_t)i1 * 64 + cbase);
    uint4 w2 = *(const uint4*)(HS + (size_t)i2 * 64 + cbase);
    uint4 w3 = *(const uint4*)(HS + (size_t)i3 * 64 + cbase);
    A.add(w0); A.add(w1); A.add(w2); A.add(w3);
  }
  for (; j < e; j++) {
    int i0 = colidx[j];
    uint4 w0 = *(const uint4*)(HS + (size_t)i0 * 64 + cbase);
    A.add(w0);
  }

  float dv = dinv[node];
  float4 b0 = *(const float4*)(bias + cbase * 2);
  float4 b1 = *(const float4*)(bias + cbase * 2 + 4);
  float r0 = A.a0 * dv + b0.x, r1 = A.a1 * dv + b0.y;
  float r2 = A.a2 * dv + b0.z, r3 = A.a3 * dv + b0.w;
  float r4 = A.a4 * dv + b1.x, r5 = A.a5 * dv + b1.y;
  float r6 = A.a6 * dv + b1.z, r7 = A.a7 * dv + b1.w;
  if (do_relu) {
    r0 = fmaxf(r0, 0.f); r1 = fmaxf(r1, 0.f); r2 = fmaxf(r2, 0.f); r3 = fmaxf(r3, 0.f);
    r4 = fmaxf(r4, 0.f); r5 = fmaxf(r5, 0.f); r6 = fmaxf(r6, 0.f); r7 = fmaxf(r7, 0.f);
  }
  uint4 o;
  o.x = pack2(r0, r1); o.y = pack2(r2, r3); o.z = pack2(r4, r5); o.w = pack2(r6, r7);
  *(uint4*)(OUT + (size_t)node * 64 + cbase) = o;
}

// ---------------- pooling: mean over sorted batch ranges ----------------
__device__ __forceinline__ int lower_bound_i(const int* a, int n, int key, int shift) {
  int lo = 0, hi = n;
  while (lo < hi) {
    int mid = (lo + hi) >> 1;
    if (a[mid << shift] < key) lo = mid + 1; else hi = mid;
  }
  return lo;
}

__global__ __launch_bounds__(256) void pool_k(const u32* __restrict__ H,
                                              const int* __restrict__ batch,
                                              const int* __restrict__ flag,
                                              float* __restrict__ OUT) {
  int g = blockIdx.x;
  int m = *flag;   // 1 if int64 batch
  int lo = lower_bound_i(batch, N_NODES, g, m);
  int hi = lower_bound_i(batch, N_NODES, g + 1, m);
  int cnt = hi - lo;
  int d2 = threadIdx.x & 63;
  int half = threadIdx.x >> 6;
  float a0 = 0.f, a1 = 0.f;
  for (int row = lo + half; row < hi; row += 4) {
    u32 v = H[(size_t)row * 64 + d2];
    a0 += bflo(v); a1 += bfhi(v);
  }
  __shared__ float red0[256], red1[256];
  red0[threadIdx.x] = a0; red1[threadIdx.x] = a1;
  __syncthreads();
  if (threadIdx.x < 64) {
    float s0 = red0[d2] + red0[d2 + 64] + red0[d2 + 128] + red0[d2 + 192];
    float s1 = red1[d2] + red1[d2 + 64] + red1[d2 + 128] + red1[d2 + 192];
    float inv = 1.0f / fmaxf((float)cnt, 1.0f);
    OUT[g * DFEAT + 2 * d2]     = s0 * inv;
    OUT[g * DFEAT + 2 * d2 + 1] = s1 * inv;
  }
}

// ---------------- orchestration ----------------

extern "C" void kernel_launch(void* const* d_in, const int* in_sizes, int n_in,
                              void* d_out, int out_size, void* d_ws, size_t ws_size,
                              hipStream_t stream) {
  const float* x   = (const float*)d_in[0];
  const int* ei    = (const int*)d_in[1];
  const int* batch = (const int*)d_in[2];
  const float* W1  = (const float*)d_in[3];
  const float* b1  = (const float*)d_in[4];
  const float* W2  = (const float*)d_in[5];
  const float* b2  = (const float*)d_in[6];
  const float* W3  = (const float*)d_in[7];
  const float* b3  = (const float*)d_in[8];
  float* out = (float*)d_out;

  char* p = (char*)d_ws;
  size_t off = 0;
  auto carve = [&](size_t bytes) -> void* {
    void* q = p + off;
    off = (off + bytes + 255) & ~(size_t)255;
    return q;
  };
  int*   flag   = (int*)carve(256);
  int*   ghist  = (int*)carve((size_t)NBLK_E * NBKT * 4);   // becomes obase in-place
  int*   gtot   = (int*)carve(NBKT * 4);
  int*   rowptr = (int*)carve((N_NODES + 1) * 4);
  float* dinv   = (float*)carve(N_NODES * 4);
  u32*   colpk  = (u32*)carve((size_t)N_EDGES * 4);
  int*   colarr = (int*)carve((size_t)N_EDGES * 4);
  u16*   Wt1    = (u16*)carve(DFEAT * DFEAT * 2);
  u16*   Wt2    = (u16*)carve(DFEAT * DFEAT * 2);
  u16*   Wt3    = (u16*)carve(DFEAT * DFEAT * 2);
  u32*   bufA   = (u32*)carve((size_t)N_NODES * 64 * 4);
  u32*   bufB   = (u32*)carve((size_t)N_NODES * 64 * 4);
  (void)ws_size;

  histA_k<<<NBLK_E + 4, 256, 0, stream>>>(ei, ghist, W1, W2, W3, Wt1, Wt2, Wt3, flag);
  scanB1_k<<<NBKT, 256, 0, stream>>>(ghist, gtot);
  scatterC_k<<<NBLK_E, 256, 0, stream>>>(ei, ghist, gtot, colpk);
  fillD_k<<<NBKT, 256, 0, stream>>>(gtot, colpk, colarr, rowptr, dinv);

  const int GB = (N_NODES + GROWS - 1) / GROWS;   // 1563

  gemm_scale_k<<<GB, 256, 0, stream>>>((const void*)x, 1, Wt1, dinv, (u16*)bufA, N_NODES);
  agg_k<<<AGG_GRID, 256, 0, stream>>>(bufA, dinv, rowptr, colarr, b1, bufB, 1);
  gemm_scale_k<<<GB, 256, 0, stream>>>((const void*)bufB, 0, Wt2, dinv, (u16*)bufA, N_NODES);
  agg_k<<<AGG_GRID, 256, 0, stream>>>(bufA, dinv, rowptr, colarr, b2, bufB, 1);
  gemm_scale_k<<<GB, 256, 0, stream>>>((const void*)bufB, 0, Wt3, dinv, (u16*)bufA, N_NODES);
  agg_k<<<AGG_GRID, 256, 0, stream>>>(bufA, dinv, rowptr, colarr, b3, bufB, 0);
  pool_k<<<N_GRAPHS, 256, 0, stream>>>(bufB, batch, flag, out);
}

// Round 4
// 388.972 us; speedup vs baseline: 1.1421x; 1.1421x over previous
//
#include <hip/hip_runtime.h>
#include <stdint.h>

typedef unsigned short u16;
typedef unsigned int   u32;

#define N_NODES  100000
#define N_EDGES  1600000
#define DFEAT    128
#define N_GRAPHS 512

#define NBKT   391    // buckets of 256 nodes (ceil(N/256))
#define EPB    8192   // edges per block in hist/scatter
#define NBLK_E 196    // ceil(N_EDGES/EPB)
#define LBUF   8192   // per-bucket capacity (mean 4096, sigma ~64)

typedef float f32x4 __attribute__((ext_vector_type(4)));
typedef short s16x8 __attribute__((ext_vector_type(8)));

__device__ __forceinline__ float bflo(u32 u) { return __uint_as_float(u << 16); }
__device__ __forceinline__ float bfhi(u32 u) { return __uint_as_float(u & 0xffff0000u); }
__device__ __forceinline__ u16 f2bf(float f) {
  u32 u = __float_as_uint(f);
  return (u16)((u + 0x7fffu + ((u >> 16) & 1u)) >> 16);   // RNE
}
__device__ __forceinline__ u32 pack2(float f0, float f1) {
  return (u32)f2bf(f0) | ((u32)f2bf(f1) << 16);
}

__device__ __forceinline__ int ld_src(const int* ei, int m, int e) {
  return m ? ei[2 * e] : ei[e];
}
__device__ __forceinline__ int ld_dst(const int* ei, int m, int e) {
  return m ? ei[2 * (N_EDGES + e)] : ei[N_EDGES + e];
}

// block-local int64-vs-int32 detect (odd words of first 64 edge slots all zero <=> int64)
__device__ __forceinline__ int detect_m_block(const int* __restrict__ ei, int* sm) {
  int t = threadIdx.x;
  if (t < 64) {
    int v = ei[2 * t + 1];
    unsigned long long b = __ballot(v != 0);
    if (t == 0) *sm = (b == 0ull) ? 1 : 0;
  }
  __syncthreads();
  return *sm;
}

// ---------------- pass A: per-block bucket histogram + W cvt + flag ----------------
__global__ __launch_bounds__(256) void histA_k(const int* __restrict__ ei,
                                               int* __restrict__ ghist,
                                               const float* __restrict__ W1,
                                               const float* __restrict__ W2,
                                               const float* __restrict__ W3,
                                               u16* __restrict__ T1, u16* __restrict__ T2,
                                               u16* __restrict__ T3, int* __restrict__ flag) {
  int t = threadIdx.x, b = blockIdx.x;
  if (b >= NBLK_E) {
    int r = b - NBLK_E;
    if (r < 3) {   // W transpose+convert
      const float* W = (r == 0) ? W1 : (r == 1) ? W2 : W3;
      u16* T         = (r == 0) ? T1 : (r == 1) ? T2 : T3;
      for (int i = t; i < DFEAT * DFEAT; i += 256) {
        int n = i >> 7, k = i & 127;
        T[i] = f2bf(W[k * DFEAT + n]);
      }
    } else {       // flag for pool_k
      if (t < 64) {
        int v = ei[2 * t + 1];
        unsigned long long mm = __ballot(v != 0);
        if (t == 0) *flag = (mm == 0ull) ? 1 : 0;
      }
    }
    return;
  }
  __shared__ int sm;
  __shared__ int hist[NBKT];
  int m = detect_m_block(ei, &sm);
  for (int i = t; i < NBKT; i += 256) hist[i] = 0;
  __syncthreads();
  int e0 = b * EPB;
#pragma unroll
  for (int p = 0; p < EPB / 256; p++) {
    int e = e0 + p * 256 + t;
    if (e < N_EDGES) atomicAdd(&hist[ld_dst(ei, m, e) >> 8], 1);
  }
  __syncthreads();
  for (int i = t; i < NBKT; i += 256) ghist[b * NBKT + i] = hist[i];
}

// ---------------- pass B: per-bucket exclusive scan over blocks ----------------
__global__ __launch_bounds__(256) void scanB1_k(int* __restrict__ ghist,
                                                int* __restrict__ gtot) {
  __shared__ int ts[256];
  int t = threadIdx.x, k = blockIdx.x;
  int v = (t < NBLK_E) ? ghist[t * NBKT + k] : 0;
  ts[t] = v;
  for (int off = 1; off < 256; off <<= 1) {
    __syncthreads(); int add = (t >= off) ? ts[t - off] : 0;
    __syncthreads(); ts[t] += add;
  }
  __syncthreads();
  if (t < NBLK_E) ghist[t * NBKT + k] = ts[t] - v;
  if (t == 255) gtot[k] = ts[255];
}

// in-block exclusive scan of gtot[NBKT] -> bb[NBKT+1]
__device__ __forceinline__ void scan_gtot_block(const int* __restrict__ gtot,
                                                int* bb, int* sc) {
  int t = threadIdx.x;
  int v0 = gtot[t];
  sc[t] = v0;
  for (int off = 1; off < 256; off <<= 1) {
    __syncthreads(); int add = (t >= off) ? sc[t - off] : 0;
    __syncthreads(); sc[t] += add;
  }
  __syncthreads();
  bb[t] = sc[t] - v0;
  int base256 = sc[255];
  __syncthreads();
  int v1 = (t < NBKT - 256) ? gtot[256 + t] : 0;
  sc[t] = v1;
  for (int off = 1; off < 256; off <<= 1) {
    __syncthreads(); int add = (t >= off) ? sc[t - off] : 0;
    __syncthreads(); sc[t] += add;
  }
  __syncthreads();
  if (t < NBKT - 256) bb[256 + t] = base256 + sc[t] - v1;
  if (t == 0) bb[NBKT] = N_EDGES;
  __syncthreads();
}

// ---------------- pass C: place edges into bucket regions ----------------
__global__ __launch_bounds__(256) void scatterC_k(const int* __restrict__ ei,
                                                  const int* __restrict__ obase,
                                                  const int* __restrict__ gtot,
                                                  u32* __restrict__ colpk) {
  __shared__ int sm;
  __shared__ int cur[NBKT];
  __shared__ int bb[NBKT + 1];
  __shared__ int sc[256];
  int t = threadIdx.x, b = blockIdx.x;
  int m = detect_m_block(ei, &sm);
  scan_gtot_block(gtot, bb, sc);
  for (int i = t; i < NBKT; i += 256) cur[i] = bb[i] + obase[b * NBKT + i];
  __syncthreads();
  int e0 = b * EPB;
#pragma unroll
  for (int p = 0; p < EPB / 256; p++) {
    int e = e0 + p * 256 + t;
    if (e < N_EDGES) {
      int d = ld_dst(ei, m, e);
      int s = ld_src(ei, m, e);
      int pos = atomicAdd(&cur[d >> 8], 1);
      colpk[pos] = (u32)s | ((u32)(d & 255) << 24);
    }
  }
}

// ---------------- pass D: degrees, rowptr, dinv, exact CSR placement ----------------
__global__ __launch_bounds__(256) void fillD_k(const int* __restrict__ gtot,
                                               const u32* __restrict__ colpk,
                                               int* __restrict__ colarr,
                                               int* __restrict__ rowptr,
                                               float* __restrict__ dinv) {
  __shared__ int hist[256];
  __shared__ int cur[256];
  __shared__ int lbuf[LBUF];
  __shared__ int bb[NBKT + 1];
  __shared__ int sc[256];
  int t = threadIdx.x, b = blockIdx.x;
  scan_gtot_block(gtot, bb, sc);
  int base = bb[b], end = bb[b + 1], cnt = end - base;
  hist[t] = 0;
  __syncthreads();
  for (int i = t; i < cnt; i += 256) atomicAdd(&hist[colpk[base + i] >> 24], 1);
  __syncthreads();
  int c = hist[t];
  cur[t] = c;
  for (int off = 1; off < 256; off <<= 1) {
    __syncthreads(); int add = (t >= off) ? cur[t - off] : 0;
    __syncthreads(); cur[t] += add;
  }
  __syncthreads();
  int excl = cur[t] - c;
  int node = b * 256 + t;
  if (node < N_NODES) {
    rowptr[node] = base + excl;
    dinv[node] = rsqrtf((float)(c + 1));      // +1 self-loop
  }
  if (b == NBKT - 1 && t == 0) rowptr[N_NODES] = N_EDGES;
  __syncthreads();
  cur[t] = excl;
  __syncthreads();
  for (int i = t; i < cnt; i += 256) {
    u32 v = colpk[base + i];
    int slot = atomicAdd(&cur[v >> 24], 1);
    if (slot < LBUF) lbuf[slot] = (int)(v & 0x00FFFFFFu);
  }
  __syncthreads();
  for (int i = t; i < cnt; i += 256) colarr[base + i] = lbuf[i];
}

// ---------------- MFMA GEMM: Y[r,:] = bf16((X @ W)[r,:] * dinv[r]) ----------------
// 128-row tile, 512 threads / 8 waves, one 16-row strip per wave.
// W staged ONCE in LDS (34.8 KB, amortized over 128 rows; r3 showed per-wave
// global W reads = 200 MB/gemm regression). X is NOT staged: each lane loads
// its own A-fragments global->registers (each X byte read exactly once per
// block), so the only barrier is the tiny W-stage and waves run free.
#define LP 136       // LDS pitch in ushorts (272B, 16B-aligned rows)
#define GROWS 128    // rows per block

__global__ __launch_bounds__(512, 4) void gemm_scale_k(const void* __restrict__ Xv,
                                                       int x_is_f32,
                                                       const u16* __restrict__ Wt,
                                                       const float* __restrict__ dinv,
                                                       u16* __restrict__ Y, int nrows) {
  __shared__ u16 sW[128 * LP];
  int tid = threadIdx.x;
  int r0 = blockIdx.x * GROWS;

  for (int c = tid; c < 2048; c += 512) {
    int row = c >> 4, off = (c & 15) * 8;
    *(uint4*)(&sW[row * LP + off]) = *(const uint4*)(Wt + row * DFEAT + off);
  }
  __syncthreads();

  int wave = tid >> 6, lane = tid & 63;
  int q = lane >> 4, r = lane & 15;
  int wr0 = wave * 16;
  int arow = r0 + wr0 + r;                 // row this lane's A-fragments come from
  bool rok = (arow < nrows);

  // A fragments: a[kk] = bf16 X[arow][kk*32 + q*8 .. +8]
  s16x8 a[4];
  if (x_is_f32) {
    const float* Xf = (const float*)Xv + (size_t)arow * DFEAT;
#pragma unroll
    for (int kk = 0; kk < 4; kk++) {
      uint4 u = make_uint4(0, 0, 0, 0);
      if (rok) {
        int k0 = kk * 32 + q * 8;
        float4 v0 = *(const float4*)(Xf + k0);
        float4 v1 = *(const float4*)(Xf + k0 + 4);
        u.x = pack2(v0.x, v0.y); u.y = pack2(v0.z, v0.w);
        u.z = pack2(v1.x, v1.y); u.w = pack2(v1.z, v1.w);
      }
      a[kk] = *(s16x8*)&u;
    }
  } else {
    const u16* Xb = (const u16*)Xv + (size_t)arow * DFEAT;
#pragma unroll
    for (int kk = 0; kk < 4; kk++) {
      uint4 u = make_uint4(0, 0, 0, 0);
      if (rok) u = *(const uint4*)(Xb + kk * 32 + q * 8);
      a[kk] = *(s16x8*)&u;
    }
  }

  f32x4 acc[8];
#pragma unroll
  for (int i = 0; i < 8; i++) acc[i] = (f32x4){0.f, 0.f, 0.f, 0.f};

#pragma unroll
  for (int kk = 0; kk < 4; kk++) {
    int k0 = kk * 32;
#pragma unroll
    for (int nt = 0; nt < 8; nt++) {
      s16x8 b = *(const s16x8*)(&sW[(nt * 16 + r) * LP + k0 + q * 8]);
      acc[nt] = __builtin_amdgcn_mfma_f32_16x16x32_bf16(a[kk], b, acc[nt], 0, 0, 0);
    }
  }

#pragma unroll
  for (int i = 0; i < 4; i++) {
    int grow = r0 + wr0 + q * 4 + i;
    if (grow < nrows) {
      float dv = dinv[grow];
#pragma unroll
      for (int nt = 0; nt < 8; nt++) {
        Y[(size_t)grow * DFEAT + nt * 16 + r] = f2bf(acc[nt][i] * dv);
      }
    }
  }
}

// ---------------- aggregation (bf16 rows, f32 accumulate) ----------------
// XCD feature-split: blocks on XCDs 0-3 (blockIdx%8 in 0..3) gather only bytes
// [0,128) of each HS row; XCDs 4-7 gather bytes [128,256). Per-XCD gather
// working set 12.8MB. unroll-4 (VGPR ~28) — unroll-8 cost occupancy with no
// BW gain (r1); BW plateaus ~3.5 TB/s across 45-68% occupancy -> path limit
// (L2-miss fill fabric). agg is within ~25% of its structural floor.
struct Acc8 {
  float a0, a1, a2, a3, a4, a5, a6, a7;
  __device__ __forceinline__ void add(uint4 v) {
    a0 += bflo(v.x); a1 += bfhi(v.x); a2 += bflo(v.y); a3 += bfhi(v.y);
    a4 += bflo(v.z); a5 += bfhi(v.z); a6 += bflo(v.w); a7 += bfhi(v.w);
  }
};

#define AGG_NB_HALF 3125               // node-blocks of 32 per half
#define AGG_GRID    6256               // 782 * 8 (covers both halves, few guarded)

__global__ __launch_bounds__(256) void agg_k(const u32* __restrict__ HS,
                                             const float* __restrict__ dinv,
                                             const int* __restrict__ rowptr,
                                             const int* __restrict__ colidx,
                                             const float* __restrict__ bias,
                                             u32* __restrict__ OUT, int do_relu) {
  int t = threadIdx.x;
  int bid = blockIdx.x;
  int res = bid & 7;                   // XCD residue (round-robin dispatch)
  int half = res >> 2;                 // 0: features 0-63, 1: features 64-127
  int nb = (bid >> 3) * 4 + (res & 3); // node-block index within this half
  if (nb >= AGG_NB_HALF) return;

  int node = nb * 32 + (t >> 3);
  int fp = t & 7;                      // which 16B chunk within the 128B half
  int cbase = half * 32 + fp * 4;      // u32 offset within the 64-u32 row

  int s = rowptr[node], e = rowptr[node + 1];

  Acc8 A;
  uint4 v = *(const uint4*)(HS + (size_t)node * 64 + cbase);   // self row
  A.a0 = bflo(v.x); A.a1 = bfhi(v.x); A.a2 = bflo(v.y); A.a3 = bfhi(v.y);
  A.a4 = bflo(v.z); A.a5 = bfhi(v.z); A.a6 = bflo(v.w); A.a7 = bfhi(v.w);

  int j = s;
  for (; j + 4 <= e; j += 4) {
    int i0 = colidx[j], i1 = colidx[j + 1], i2 = colidx[j + 2], i3 = colidx[j + 3];
    uint4 w0 = *(const uint4*)(HS + (size_t)i0 * 64 + cbase);
    uint4 w1 = *(const uint4*)(HS + (size_t)i1 * 64 + cbase);
    uint4 w2 = *(const uint4*)(HS + (size_t)i2 * 64 + cbase);
    uint4 w3 = *(const uint4*)(HS + (size_t)i3 * 64 + cbase);
    A.add(w0); A.add(w1); A.add(w2); A.add(w3);
  }
  for (; j < e; j++) {
    int i0 = colidx[j];
    uint4 w0 = *(const uint4*)(HS + (size_t)i0 * 64 + cbase);
    A.add(w0);
  }

  float dv = dinv[node];
  float4 b0 = *(const float4*)(bias + cbase * 2);
  float4 b1 = *(const float4*)(bias + cbase * 2 + 4);
  float r0 = A.a0 * dv + b0.x, r1 = A.a1 * dv + b0.y;
  float r2 = A.a2 * dv + b0.z, r3 = A.a3 * dv + b0.w;
  float r4 = A.a4 * dv + b1.x, r5 = A.a5 * dv + b1.y;
  float r6 = A.a6 * dv + b1.z, r7 = A.a7 * dv + b1.w;
  if (do_relu) {
    r0 = fmaxf(r0, 0.f); r1 = fmaxf(r1, 0.f); r2 = fmaxf(r2, 0.f); r3 = fmaxf(r3, 0.f);
    r4 = fmaxf(r4, 0.f); r5 = fmaxf(r5, 0.f); r6 = fmaxf(r6, 0.f); r7 = fmaxf(r7, 0.f);
  }
  uint4 o;
  o.x = pack2(r0, r1); o.y = pack2(r2, r3); o.z = pack2(r4, r5); o.w = pack2(r6, r7);
  *(uint4*)(OUT + (size_t)node * 64 + cbase) = o;
}

// ---------------- pooling: mean over sorted batch ranges ----------------
__device__ __forceinline__ int lower_bound_i(const int* a, int n, int key, int shift) {
  int lo = 0, hi = n;
  while (lo < hi) {
    int mid = (lo + hi) >> 1;
    if (a[mid << shift] < key) lo = mid + 1; else hi = mid;
  }
  return lo;
}

__global__ __launch_bounds__(256) void pool_k(const u32* __restrict__ H,
                                              const int* __restrict__ batch,
                                              const int* __restrict__ flag,
                                              float* __restrict__ OUT) {
  int g = blockIdx.x;
  int m = *flag;   // 1 if int64 batch
  int lo = lower_bound_i(batch, N_NODES, g, m);
  int hi = lower_bound_i(batch, N_NODES, g + 1, m);
  int cnt = hi - lo;
  int d2 = threadIdx.x & 63;
  int half = threadIdx.x >> 6;
  float a0 = 0.f, a1 = 0.f;
  for (int row = lo + half; row < hi; row += 4) {
    u32 v = H[(size_t)row * 64 + d2];
    a0 += bflo(v); a1 += bfhi(v);
  }
  __shared__ float red0[256], red1[256];
  red0[threadIdx.x] = a0; red1[threadIdx.x] = a1;
  __syncthreads();
  if (threadIdx.x < 64) {
    float s0 = red0[d2] + red0[d2 + 64] + red0[d2 + 128] + red0[d2 + 192];
    float s1 = red1[d2] + red1[d2 + 64] + red1[d2 + 128] + red1[d2 + 192];
    float inv = 1.0f / fmaxf((float)cnt, 1.0f);
    OUT[g * DFEAT + 2 * d2]     = s0 * inv;
    OUT[g * DFEAT + 2 * d2 + 1] = s1 * inv;
  }
}

// ---------------- orchestration ----------------

extern "C" void kernel_launch(void* const* d_in, const int* in_sizes, int n_in,
                              void* d_out, int out_size, void* d_ws, size_t ws_size,
                              hipStream_t stream) {
  const float* x   = (const float*)d_in[0];
  const int* ei    = (const int*)d_in[1];
  const int* batch = (const int*)d_in[2];
  const float* W1  = (const float*)d_in[3];
  const float* b1  = (const float*)d_in[4];
  const float* W2  = (const float*)d_in[5];
  const float* b2  = (const float*)d_in[6];
  const float* W3  = (const float*)d_in[7];
  const float* b3  = (const float*)d_in[8];
  float* out = (float*)d_out;

  char* p = (char*)d_ws;
  size_t off = 0;
  auto carve = [&](size_t bytes) -> void* {
    void* q = p + off;
    off = (off + bytes + 255) & ~(size_t)255;
    return q;
  };
  int*   flag   = (int*)carve(256);
  int*   ghist  = (int*)carve((size_t)NBLK_E * NBKT * 4);   // becomes obase in-place
  int*   gtot   = (int*)carve(NBKT * 4);
  int*   rowptr = (int*)carve((N_NODES + 1) * 4);
  float* dinv   = (float*)carve(N_NODES * 4);
  u32*   colpk  = (u32*)carve((size_t)N_EDGES * 4);
  int*   colarr = (int*)carve((size_t)N_EDGES * 4);
  u16*   Wt1    = (u16*)carve(DFEAT * DFEAT * 2);
  u16*   Wt2    = (u16*)carve(DFEAT * DFEAT * 2);
  u16*   Wt3    = (u16*)carve(DFEAT * DFEAT * 2);
  u32*   bufA   = (u32*)carve((size_t)N_NODES * 64 * 4);
  u32*   bufB   = (u32*)carve((size_t)N_NODES * 64 * 4);
  (void)ws_size;

  histA_k<<<NBLK_E + 4, 256, 0, stream>>>(ei, ghist, W1, W2, W3, Wt1, Wt2, Wt3, flag);
  scanB1_k<<<NBKT, 256, 0, stream>>>(ghist, gtot);
  scatterC_k<<<NBLK_E, 256, 0, stream>>>(ei, ghist, gtot, colpk);
  fillD_k<<<NBKT, 256, 0, stream>>>(gtot, colpk, colarr, rowptr, dinv);

  const int GB = (N_NODES + GROWS - 1) / GROWS;   // 782

  gemm_scale_k<<<GB, 512, 0, stream>>>((const void*)x, 1, Wt1, dinv, (u16*)bufA, N_NODES);
  agg_k<<<AGG_GRID, 256, 0, stream>>>(bufA, dinv, rowptr, colarr, b1, bufB, 1);
  gemm_scale_k<<<GB, 512, 0, stream>>>((const void*)bufB, 0, Wt2, dinv, (u16*)bufA, N_NODES);
  agg_k<<<AGG_GRID, 256, 0, stream>>>(bufA, dinv, rowptr, colarr, b2, bufB, 1);
  gemm_scale_k<<<GB, 512, 0, stream>>>((const void*)bufB, 0, Wt3, dinv, (u16*)bufA, N_NODES);
  agg_k<<<AGG_GRID, 256, 0, stream>>>(bufA, dinv, rowptr, colarr, b3, bufB, 0);
  pool_k<<<N_GRAPHS, 256, 0, stream>>>(bufB, batch, flag, out);
}

// Round 5
// 383.404 us; speedup vs baseline: 1.1587x; 1.0145x over previous
//
#include <hip/hip_runtime.h>
#include <stdint.h>

typedef unsigned short u16;
typedef unsigned int   u32;

#define N_NODES  100000
#define N_EDGES  1600000
#define DFEAT    128
#define N_GRAPHS 512

#define NBKT   391    // buckets of 256 nodes (ceil(N/256))
#define EPB    8192   // edges per block in hist/scatter
#define NBLK_E 196    // ceil(N_EDGES/EPB)
#define LBUF   8192   // per-bucket capacity (mean 4096, sigma ~64)

typedef float f32x4 __attribute__((ext_vector_type(4)));
typedef short s16x8 __attribute__((ext_vector_type(8)));

__device__ __forceinline__ float bflo(u32 u) { return __uint_as_float(u << 16); }
__device__ __forceinline__ float bfhi(u32 u) { return __uint_as_float(u & 0xffff0000u); }
__device__ __forceinline__ u16 f2bf(float f) {
  u32 u = __float_as_uint(f);
  return (u16)((u + 0x7fffu + ((u >> 16) & 1u)) >> 16);   // RNE
}
__device__ __forceinline__ u32 pack2(float f0, float f1) {
  return (u32)f2bf(f0) | ((u32)f2bf(f1) << 16);
}

__device__ __forceinline__ int ld_src(const int* ei, int m, int e) {
  return m ? ei[2 * e] : ei[e];
}
__device__ __forceinline__ int ld_dst(const int* ei, int m, int e) {
  return m ? ei[2 * (N_EDGES + e)] : ei[N_EDGES + e];
}

// block-local int64-vs-int32 detect (odd words of first 64 edge slots all zero <=> int64)
__device__ __forceinline__ int detect_m_block(const int* __restrict__ ei, int* sm) {
  int t = threadIdx.x;
  if (t < 64) {
    int v = ei[2 * t + 1];
    unsigned long long b = __ballot(v != 0);
    if (t == 0) *sm = (b == 0ull) ? 1 : 0;
  }
  __syncthreads();
  return *sm;
}

// ---------------- pass A: per-block bucket histogram + W cvt + flag ----------------
__global__ __launch_bounds__(256) void histA_k(const int* __restrict__ ei,
                                               int* __restrict__ ghist,
                                               const float* __restrict__ W1,
                                               const float* __restrict__ W2,
                                               const float* __restrict__ W3,
                                               u16* __restrict__ T1, u16* __restrict__ T2,
                                               u16* __restrict__ T3, int* __restrict__ flag) {
  int t = threadIdx.x, b = blockIdx.x;
  if (b >= NBLK_E) {
    int r = b - NBLK_E;
    if (r < 3) {   // W transpose+convert
      const float* W = (r == 0) ? W1 : (r == 1) ? W2 : W3;
      u16* T         = (r == 0) ? T1 : (r == 1) ? T2 : T3;
      for (int i = t; i < DFEAT * DFEAT; i += 256) {
        int n = i >> 7, k = i & 127;
        T[i] = f2bf(W[k * DFEAT + n]);
      }
    } else {       // flag for pool_k
      if (t < 64) {
        int v = ei[2 * t + 1];
        unsigned long long mm = __ballot(v != 0);
        if (t == 0) *flag = (mm == 0ull) ? 1 : 0;
      }
    }
    return;
  }
  __shared__ int sm;
  __shared__ int hist[NBKT];
  int m = detect_m_block(ei, &sm);
  for (int i = t; i < NBKT; i += 256) hist[i] = 0;
  __syncthreads();
  int e0 = b * EPB;
#pragma unroll
  for (int p = 0; p < EPB / 256; p++) {
    int e = e0 + p * 256 + t;
    if (e < N_EDGES) atomicAdd(&hist[ld_dst(ei, m, e) >> 8], 1);
  }
  __syncthreads();
  for (int i = t; i < NBKT; i += 256) ghist[b * NBKT + i] = hist[i];
}

// ---------------- pass B: per-bucket exclusive scan over blocks ----------------
__global__ __launch_bounds__(256) void scanB1_k(int* __restrict__ ghist,
                                                int* __restrict__ gtot) {
  __shared__ int ts[256];
  int t = threadIdx.x, k = blockIdx.x;
  int v = (t < NBLK_E) ? ghist[t * NBKT + k] : 0;
  ts[t] = v;
  for (int off = 1; off < 256; off <<= 1) {
    __syncthreads(); int add = (t >= off) ? ts[t - off] : 0;
    __syncthreads(); ts[t] += add;
  }
  __syncthreads();
  if (t < NBLK_E) ghist[t * NBKT + k] = ts[t] - v;
  if (t == 255) gtot[k] = ts[255];
}

// in-block exclusive scan of gtot[NBKT] -> bb[NBKT+1]
__device__ __forceinline__ void scan_gtot_block(const int* __restrict__ gtot,
                                                int* bb, int* sc) {
  int t = threadIdx.x;
  int v0 = gtot[t];
  sc[t] = v0;
  for (int off = 1; off < 256; off <<= 1) {
    __syncthreads(); int add = (t >= off) ? sc[t - off] : 0;
    __syncthreads(); sc[t] += add;
  }
  __syncthreads();
  bb[t] = sc[t] - v0;
  int base256 = sc[255];
  __syncthreads();
  int v1 = (t < NBKT - 256) ? gtot[256 + t] : 0;
  sc[t] = v1;
  for (int off = 1; off < 256; off <<= 1) {
    __syncthreads(); int add = (t >= off) ? sc[t - off] : 0;
    __syncthreads(); sc[t] += add;
  }
  __syncthreads();
  if (t < NBKT - 256) bb[256 + t] = base256 + sc[t] - v1;
  if (t == 0) bb[NBKT] = N_EDGES;
  __syncthreads();
}

// ---------------- pass C: place edges into bucket regions ----------------
__global__ __launch_bounds__(256) void scatterC_k(const int* __restrict__ ei,
                                                  const int* __restrict__ obase,
                                                  const int* __restrict__ gtot,
                                                  u32* __restrict__ colpk) {
  __shared__ int sm;
  __shared__ int cur[NBKT];
  __shared__ int bb[NBKT + 1];
  __shared__ int sc[256];
  int t = threadIdx.x, b = blockIdx.x;
  int m = detect_m_block(ei, &sm);
  scan_gtot_block(gtot, bb, sc);
  for (int i = t; i < NBKT; i += 256) cur[i] = bb[i] + obase[b * NBKT + i];
  __syncthreads();
  int e0 = b * EPB;
#pragma unroll
  for (int p = 0; p < EPB / 256; p++) {
    int e = e0 + p * 256 + t;
    if (e < N_EDGES) {
      int d = ld_dst(ei, m, e);
      int s = ld_src(ei, m, e);
      int pos = atomicAdd(&cur[d >> 8], 1);
      colpk[pos] = (u32)s | ((u32)(d & 255) << 24);
    }
  }
}

// ---------------- pass D: degrees, rowptr, dinv, exact CSR placement ----------------
__global__ __launch_bounds__(256) void fillD_k(const int* __restrict__ gtot,
                                               const u32* __restrict__ colpk,
                                               int* __restrict__ colarr,
                                               int* __restrict__ rowptr,
                                               float* __restrict__ dinv) {
  __shared__ int hist[256];
  __shared__ int cur[256];
  __shared__ int lbuf[LBUF];
  __shared__ int bb[NBKT + 1];
  __shared__ int sc[256];
  int t = threadIdx.x, b = blockIdx.x;
  scan_gtot_block(gtot, bb, sc);
  int base = bb[b], end = bb[b + 1], cnt = end - base;
  hist[t] = 0;
  __syncthreads();
  for (int i = t; i < cnt; i += 256) atomicAdd(&hist[colpk[base + i] >> 24], 1);
  __syncthreads();
  int c = hist[t];
  cur[t] = c;
  for (int off = 1; off < 256; off <<= 1) {
    __syncthreads(); int add = (t >= off) ? cur[t - off] : 0;
    __syncthreads(); cur[t] += add;
  }
  __syncthreads();
  int excl = cur[t] - c;
  int node = b * 256 + t;
  if (node < N_NODES) {
    rowptr[node] = base + excl;
    dinv[node] = rsqrtf((float)(c + 1));      // +1 self-loop
  }
  if (b == NBKT - 1 && t == 0) rowptr[N_NODES] = N_EDGES;
  __syncthreads();
  cur[t] = excl;
  __syncthreads();
  for (int i = t; i < cnt; i += 256) {
    u32 v = colpk[base + i];
    int slot = atomicAdd(&cur[v >> 24], 1);
    if (slot < LBUF) lbuf[slot] = (int)(v & 0x00FFFFFFu);
  }
  __syncthreads();
  for (int i = t; i < cnt; i += 256) colarr[base + i] = lbuf[i];
}

// ---------------- MFMA GEMM: Y[r,:] = bf16((X @ W)[r,:] * dinv[r]) ----------------
// 128-row tile, 512 threads / 8 waves, one 16-row strip per wave.
// W staged ONCE in LDS; X loaded directly to registers (r4).
// r5: LDS-transposed epilogue — MFMA C-fragments are 2B stores at 32B stride
// (32 stores/thread, sub-64B-granule write amplification). Dump acc to the
// dead sW buffer as bf16, then stream coalesced uint4 rows (4 stores/thread).
#define LP 136       // LDS pitch in ushorts (272B, 16B-aligned rows)
#define GROWS 128    // rows per block

__global__ __launch_bounds__(512, 4) void gemm_scale_k(const void* __restrict__ Xv,
                                                       int x_is_f32,
                                                       const u16* __restrict__ Wt,
                                                       const float* __restrict__ dinv,
                                                       u16* __restrict__ Y, int nrows) {
  __shared__ u16 sW[128 * LP];
  int tid = threadIdx.x;
  int r0 = blockIdx.x * GROWS;

  for (int c = tid; c < 2048; c += 512) {
    int row = c >> 4, off = (c & 15) * 8;
    *(uint4*)(&sW[row * LP + off]) = *(const uint4*)(Wt + row * DFEAT + off);
  }
  __syncthreads();

  int wave = tid >> 6, lane = tid & 63;
  int q = lane >> 4, r = lane & 15;
  int wr0 = wave * 16;
  int arow = r0 + wr0 + r;                 // row this lane's A-fragments come from
  bool rok = (arow < nrows);

  // A fragments: a[kk] = bf16 X[arow][kk*32 + q*8 .. +8]
  s16x8 a[4];
  if (x_is_f32) {
    const float* Xf = (const float*)Xv + (size_t)arow * DFEAT;
#pragma unroll
    for (int kk = 0; kk < 4; kk++) {
      uint4 u = make_uint4(0, 0, 0, 0);
      if (rok) {
        int k0 = kk * 32 + q * 8;
        float4 v0 = *(const float4*)(Xf + k0);
        float4 v1 = *(const float4*)(Xf + k0 + 4);
        u.x = pack2(v0.x, v0.y); u.y = pack2(v0.z, v0.w);
        u.z = pack2(v1.x, v1.y); u.w = pack2(v1.z, v1.w);
      }
      a[kk] = *(s16x8*)&u;
    }
  } else {
    const u16* Xb = (const u16*)Xv + (size_t)arow * DFEAT;
#pragma unroll
    for (int kk = 0; kk < 4; kk++) {
      uint4 u = make_uint4(0, 0, 0, 0);
      if (rok) u = *(const uint4*)(Xb + kk * 32 + q * 8);
      a[kk] = *(s16x8*)&u;
    }
  }

  f32x4 acc[8];
#pragma unroll
  for (int i = 0; i < 8; i++) acc[i] = (f32x4){0.f, 0.f, 0.f, 0.f};

#pragma unroll
  for (int kk = 0; kk < 4; kk++) {
    int k0 = kk * 32;
#pragma unroll
    for (int nt = 0; nt < 8; nt++) {
      s16x8 b = *(const s16x8*)(&sW[(nt * 16 + r) * LP + k0 + q * 8]);
      acc[nt] = __builtin_amdgcn_mfma_f32_16x16x32_bf16(a[kk], b, acc[nt], 0, 0, 0);
    }
  }

  // ---- epilogue: acc -> LDS (bf16, row-major) -> coalesced uint4 stores ----
  __syncthreads();            // all sW reads done; safe to overwrite
#pragma unroll
  for (int i = 0; i < 4; i++) {
    int row = wr0 + q * 4 + i;           // 0..127 within tile
    int grow = r0 + row;
    float dv = (grow < nrows) ? dinv[grow] : 0.0f;
#pragma unroll
    for (int nt = 0; nt < 8; nt++) {
      sW[row * LP + nt * 16 + r] = f2bf(acc[nt][i] * dv);
    }
  }
  __syncthreads();
  for (int c = tid; c < 128 * 16; c += 512) {
    int row = c >> 4, seg = c & 15;
    int grow = r0 + row;
    if (grow < nrows) {
      *(uint4*)(Y + (size_t)grow * DFEAT + seg * 8) = *(const uint4*)(&sW[row * LP + seg * 8]);
    }
  }
}

// ---------------- aggregation (bf16 rows, f32 accumulate) ----------------
// XCD feature-split: blocks on XCDs 0-3 (blockIdx%8 in 0..3) gather only bytes
// [0,128) of each HS row; XCDs 4-7 gather bytes [128,256). Per-XCD gather
// working set 12.8MB. unroll-4 (VGPR ~28) — unroll-8 cost occupancy with no
// BW gain (r1); BW plateaus ~3.5 TB/s across 45-68% occupancy -> path limit
// (L2-miss fill fabric). agg is within ~25% of its structural floor.
struct Acc8 {
  float a0, a1, a2, a3, a4, a5, a6, a7;
  __device__ __forceinline__ void add(uint4 v) {
    a0 += bflo(v.x); a1 += bfhi(v.x); a2 += bflo(v.y); a3 += bfhi(v.y);
    a4 += bflo(v.z); a5 += bfhi(v.z); a6 += bflo(v.w); a7 += bfhi(v.w);
  }
};

#define AGG_NB_HALF 3125               // node-blocks of 32 per half
#define AGG_GRID    6256               // 782 * 8 (covers both halves, few guarded)

__global__ __launch_bounds__(256) void agg_k(const u32* __restrict__ HS,
                                             const float* __restrict__ dinv,
                                             const int* __restrict__ rowptr,
                                             const int* __restrict__ colidx,
                                             const float* __restrict__ bias,
                                             u32* __restrict__ OUT, int do_relu) {
  int t = threadIdx.x;
  int bid = blockIdx.x;
  int res = bid & 7;                   // XCD residue (round-robin dispatch)
  int half = res >> 2;                 // 0: features 0-63, 1: features 64-127
  int nb = (bid >> 3) * 4 + (res & 3); // node-block index within this half
  if (nb >= AGG_NB_HALF) return;

  int node = nb * 32 + (t >> 3);
  int fp = t & 7;                      // which 16B chunk within the 128B half
  int cbase = half * 32 + fp * 4;      // u32 offset within the 64-u32 row

  int s = rowptr[node], e = rowptr[node + 1];

  Acc8 A;
  uint4 v = *(const uint4*)(HS + (size_t)node * 64 + cbase);   // self row
  A.a0 = bflo(v.x); A.a1 = bfhi(v.x); A.a2 = bflo(v.y); A.a3 = bfhi(v.y);
  A.a4 = bflo(v.z); A.a5 = bfhi(v.z); A.a6 = bflo(v.w); A.a7 = bfhi(v.w);

  int j = s;
  for (; j + 4 <= e; j += 4) {
    int i0 = colidx[j], i1 = colidx[j + 1], i2 = colidx[j + 2], i3 = colidx[j + 3];
    uint4 w0 = *(const uint4*)(HS + (size_t)i0 * 64 + cbase);
    uint4 w1 = *(const uint4*)(HS + (size_t)i1 * 64 + cbase);
    uint4 w2 = *(const uint4*)(HS + (size_t)i2 * 64 + cbase);
    uint4 w3 = *(const uint4*)(HS + (size_t)i3 * 64 + cbase);
    A.add(w0); A.add(w1); A.add(w2); A.add(w3);
  }
  for (; j < e; j++) {
    int i0 = colidx[j];
    uint4 w0 = *(const uint4*)(HS + (size_t)i0 * 64 + cbase);
    A.add(w0);
  }

  float dv = dinv[node];
  float4 b0 = *(const float4*)(bias + cbase * 2);
  float4 b1 = *(const float4*)(bias + cbase * 2 + 4);
  float r0 = A.a0 * dv + b0.x, r1 = A.a1 * dv + b0.y;
  float r2 = A.a2 * dv + b0.z, r3 = A.a3 * dv + b0.w;
  float r4 = A.a4 * dv + b1.x, r5 = A.a5 * dv + b1.y;
  float r6 = A.a6 * dv + b1.z, r7 = A.a7 * dv + b1.w;
  if (do_relu) {
    r0 = fmaxf(r0, 0.f); r1 = fmaxf(r1, 0.f); r2 = fmaxf(r2, 0.f); r3 = fmaxf(r3, 0.f);
    r4 = fmaxf(r4, 0.f); r5 = fmaxf(r5, 0.f); r6 = fmaxf(r6, 0.f); r7 = fmaxf(r7, 0.f);
  }
  uint4 o;
  o.x = pack2(r0, r1); o.y = pack2(r2, r3); o.z = pack2(r4, r5); o.w = pack2(r6, r7);
  *(uint4*)(OUT + (size_t)node * 64 + cbase) = o;
}

// ---------------- pooling: mean over sorted batch ranges ----------------
__device__ __forceinline__ int lower_bound_i(const int* a, int n, int key, int shift) {
  int lo = 0, hi = n;
  while (lo < hi) {
    int mid = (lo + hi) >> 1;
    if (a[mid << shift] < key) lo = mid + 1; else hi = mid;
  }
  return lo;
}

__global__ __launch_bounds__(256) void pool_k(const u32* __restrict__ H,
                                              const int* __restrict__ batch,
                                              const int* __restrict__ flag,
                                              float* __restrict__ OUT) {
  int g = blockIdx.x;
  int m = *flag;   // 1 if int64 batch
  int lo = lower_bound_i(batch, N_NODES, g, m);
  int hi = lower_bound_i(batch, N_NODES, g + 1, m);
  int cnt = hi - lo;
  int d2 = threadIdx.x & 63;
  int half = threadIdx.x >> 6;
  float a0 = 0.f, a1 = 0.f;
  for (int row = lo + half; row < hi; row += 4) {
    u32 v = H[(size_t)row * 64 + d2];
    a0 += bflo(v); a1 += bfhi(v);
  }
  __shared__ float red0[256], red1[256];
  red0[threadIdx.x] = a0; red1[threadIdx.x] = a1;
  __syncthreads();
  if (threadIdx.x < 64) {
    float s0 = red0[d2] + red0[d2 + 64] + red0[d2 + 128] + red0[d2 + 192];
    float s1 = red1[d2] + red1[d2 + 64] + red1[d2 + 128] + red1[d2 + 192];
    float inv = 1.0f / fmaxf((float)cnt, 1.0f);
    OUT[g * DFEAT + 2 * d2]     = s0 * inv;
    OUT[g * DFEAT + 2 * d2 + 1] = s1 * inv;
  }
}

// ---------------- orchestration ----------------

extern "C" void kernel_launch(void* const* d_in, const int* in_sizes, int n_in,
                              void* d_out, int out_size, void* d_ws, size_t ws_size,
                              hipStream_t stream) {
  const float* x   = (const float*)d_in[0];
  const int* ei    = (const int*)d_in[1];
  const int* batch = (const int*)d_in[2];
  const float* W1  = (const float*)d_in[3];
  const float* b1  = (const float*)d_in[4];
  const float* W2  = (const float*)d_in[5];
  const float* b2  = (const float*)d_in[6];
  const float* W3  = (const float*)d_in[7];
  const float* b3  = (const float*)d_in[8];
  float* out = (float*)d_out;

  char* p = (char*)d_ws;
  size_t off = 0;
  auto carve = [&](size_t bytes) -> void* {
    void* q = p + off;
    off = (off + bytes + 255) & ~(size_t)255;
    return q;
  };
  int*   flag   = (int*)carve(256);
  int*   ghist  = (int*)carve((size_t)NBLK_E * NBKT * 4);   // becomes obase in-place
  int*   gtot   = (int*)carve(NBKT * 4);
  int*   rowptr = (int*)carve((N_NODES + 1) * 4);
  float* dinv   = (float*)carve(N_NODES * 4);
  u32*   colpk  = (u32*)carve((size_t)N_EDGES * 4);
  int*   colarr = (int*)carve((size_t)N_EDGES * 4);
  u16*   Wt1    = (u16*)carve(DFEAT * DFEAT * 2);
  u16*   Wt2    = (u16*)carve(DFEAT * DFEAT * 2);
  u16*   Wt3    = (u16*)carve(DFEAT * DFEAT * 2);
  u32*   bufA   = (u32*)carve((size_t)N_NODES * 64 * 4);
  u32*   bufB   = (u32*)carve((size_t)N_NODES * 64 * 4);
  (void)ws_size;

  histA_k<<<NBLK_E + 4, 256, 0, stream>>>(ei, ghist, W1, W2, W3, Wt1, Wt2, Wt3, flag);
  scanB1_k<<<NBKT, 256, 0, stream>>>(ghist, gtot);
  scatterC_k<<<NBLK_E, 256, 0, stream>>>(ei, ghist, gtot, colpk);
  fillD_k<<<NBKT, 256, 0, stream>>>(gtot, colpk, colarr, rowptr, dinv);

  const int GB = (N_NODES + GROWS - 1) / GROWS;   // 782

  gemm_scale_k<<<GB, 512, 0, stream>>>((const void*)x, 1, Wt1, dinv, (u16*)bufA, N_NODES);
  agg_k<<<AGG_GRID, 256, 0, stream>>>(bufA, dinv, rowptr, colarr, b1, bufB, 1);
  gemm_scale_k<<<GB, 512, 0, stream>>>((const void*)bufB, 0, Wt2, dinv, (u16*)bufA, N_NODES);
  agg_k<<<AGG_GRID, 256, 0, stream>>>(bufA, dinv, rowptr, colarr, b2, bufB, 1);
  gemm_scale_k<<<GB, 512, 0, stream>>>((const void*)bufB, 0, Wt3, dinv, (u16*)bufA, N_NODES);
  agg_k<<<AGG_GRID, 256, 0, stream>>>(bufA, dinv, rowptr, colarr, b3, bufB, 0);
  pool_k<<<N_GRAPHS, 256, 0, stream>>>(bufB, batch, flag, out);
}